// Round 2
// baseline (8806.725 us; speedup 1.0000x reference)
//
#include <hip/hip_runtime.h>
#include <hip/hip_bf16.h>
#include <math.h>

#define N_NODES 50000
#define N_EDGES 200000
#define N_GRAPH 1024
#define HC      128
#define NFC     256
#define NLAYER  5
#define NFFC    512

enum { EPI_NONE=0, EPI_BIAS=1, EPI_SSP=2, EPI_RELU_RES=3, EPI_TANH_RES=4 };

__device__ __forceinline__ float ssp_f(float x) {
  // softplus(x) - ln(2), numerically stable (matches jax.nn.softplus)
  return fmaxf(x, 0.0f) + log1pf(expf(-fabsf(x))) - 0.69314718055994530942f;
}

// ---------------------------------------------------------------------------
__global__ void zero_kernel(float4* __restrict__ p, int n4) {
  int i = blockIdx.x * blockDim.x + threadIdx.x;
  if (i < n4) p[i] = make_float4(0.f, 0.f, 0.f, 0.f);
}

// h[N,128]: cols 0..79 = vert_emb[x], cols 80..127 = pos @ pos_w.T
__global__ void embed_kernel(const int* __restrict__ x, const float* __restrict__ pos,
                             const float* __restrict__ vert, const float* __restrict__ posw,
                             float* __restrict__ h) {
  int n = blockIdx.x;
  int c = threadIdx.x;            // 128 threads
  float v;
  if (c < 80) {
    v = vert[(size_t)x[n] * 80 + c];
  } else {
    int j = c - 80;
    v = pos[n*3+0]*posw[j*3+0] + pos[n*3+1]*posw[j*3+1] + pos[n*3+2]*posw[j*3+2];
  }
  h[(size_t)n*HC + c] = v;
}

// ea[E,128] = edge_attr[E,4] @ edge_w[128,4].T
__global__ void edgeproj_kernel(const float* __restrict__ eattr, const float* __restrict__ ew,
                                float* __restrict__ ea) {
  int idx = blockIdx.x * blockDim.x + threadIdx.x;
  if (idx >= N_EDGES * HC) return;
  int e = idx >> 7, c = idx & 127;
  const float* a = eattr + (size_t)e*4;
  const float* w = ew + (size_t)c*4;
  ea[idx] = a[0]*w[0] + a[1]*w[1] + a[2]*w[2] + a[3]*w[3];
}

// ---------------------------------------------------------------------------
// C[M,N] = epi(A @ Bw^T + bias) (+ resid).  Bw layout [N][K] row-major.
// A is optionally a K-concat of A0 (first K0 cols) and A1 (remaining K-K0).
// BM=64, BN=128, BK=16, 256 threads, 4x8 micro-tile.
// NOTE: resid/C intentionally NOT __restrict__ — in-place variants alias A0.
template<int EPI>
__global__ __launch_bounds__(256) void gemm_kernel(
    const float* A0, const float* A1, int K0,
    const float* __restrict__ Bw, const float* __restrict__ bias,
    const float* resid, float* C,
    int M, int K, int N)
{
  constexpr int BM=64, BN=128, BK=16;
  __shared__ float As[BK][BM+4];
  __shared__ float Bs[BK][BN+4];
  const int tid = threadIdx.x;
  const int m0 = blockIdx.x * BM;
  const int n0 = blockIdx.y * BN;
  const int tx = tid & 15;          // col group
  const int ty = tid >> 4;          // row group
  const int lr = tid >> 2;          // load row 0..63
  const int lk = (tid & 3) << 2;    // load k offset 0,4,8,12

  float acc[4][8];
#pragma unroll
  for (int i=0;i<4;i++)
#pragma unroll
    for (int j=0;j<8;j++) acc[i][j]=0.0f;

  const int KA1 = K - K0;
  const int am = m0 + lr;
  for (int kk = 0; kk < K; kk += BK) {
    float4 av = make_float4(0.f,0.f,0.f,0.f);
    const int kg = kk + lk;
    if (am < M) {
      const float* ap = (kg < K0) ? (A0 + (size_t)am*K0 + kg)
                                  : (A1 + (size_t)am*KA1 + (kg - K0));
      av = *(const float4*)ap;
    }
    const float4 bv0 = *(const float4*)(Bw + (size_t)(n0+lr)*K + kg);
    const float4 bv1 = *(const float4*)(Bw + (size_t)(n0+lr+64)*K + kg);
    __syncthreads();
    As[lk+0][lr]=av.x; As[lk+1][lr]=av.y; As[lk+2][lr]=av.z; As[lk+3][lr]=av.w;
    Bs[lk+0][lr]=bv0.x; Bs[lk+1][lr]=bv0.y; Bs[lk+2][lr]=bv0.z; Bs[lk+3][lr]=bv0.w;
    Bs[lk+0][lr+64]=bv1.x; Bs[lk+1][lr+64]=bv1.y; Bs[lk+2][lr+64]=bv1.z; Bs[lk+3][lr+64]=bv1.w;
    __syncthreads();
#pragma unroll
    for (int k=0;k<BK;k++) {
      float a[4], b[8];
#pragma unroll
      for (int i=0;i<4;i++) a[i] = As[k][ty*4+i];
#pragma unroll
      for (int j=0;j<4;j++) { b[j] = Bs[k][tx*4+j]; b[4+j] = Bs[k][64+tx*4+j]; }
#pragma unroll
      for (int i=0;i<4;i++)
#pragma unroll
        for (int j=0;j<8;j++) acc[i][j] = fmaf(a[i], b[j], acc[i][j]);
    }
  }

  float bvals[8];
  if constexpr (EPI != EPI_NONE) {
#pragma unroll
    for (int j=0;j<4;j++) { bvals[j] = bias[n0+tx*4+j]; bvals[4+j] = bias[n0+64+tx*4+j]; }
  }
#pragma unroll
  for (int i=0;i<4;i++) {
    const int m = m0 + ty*4 + i;
    if (m < M) {
      float vs[8];
#pragma unroll
      for (int j=0;j<8;j++) {
        float v = acc[i][j];
        if constexpr (EPI != EPI_NONE) v += bvals[j];
        if constexpr (EPI == EPI_SSP)       v = ssp_f(v);
        else if constexpr (EPI == EPI_RELU_RES) v = fmaxf(v, 0.0f);
        else if constexpr (EPI == EPI_TANH_RES) v = tanhf(v);
        vs[j] = v;
      }
      if constexpr (EPI == EPI_RELU_RES || EPI == EPI_TANH_RES) {
        const float* r0 = resid + (size_t)m*N + n0 + tx*4;
        const float* r1 = resid + (size_t)m*N + n0 + 64 + tx*4;
#pragma unroll
        for (int j=0;j<4;j++) { vs[j] += r0[j]; vs[4+j] += r1[j]; }
      }
      float* c0 = C + (size_t)m*N + n0 + tx*4;
      float* c1 = C + (size_t)m*N + n0 + 64 + tx*4;
#pragma unroll
      for (int j=0;j<4;j++) { c0[j] = vs[j]; c1[j] = vs[4+j]; }
    }
  }
}

// ---------------------------------------------------------------------------
// agg[dst[e0+e], c] += h1[src[e0+e], c] * W[e, c]   (one block = one edge)
__global__ void scatter_kernel(const int* __restrict__ ei, int e0,
                               const float* __restrict__ h1,
                               const float* __restrict__ W, float* __restrict__ agg) {
  int e = blockIdx.x;
  int c = threadIdx.x;              // 256 threads
  int ge = e0 + e;
  int s = ei[ge];
  int d = ei[N_EDGES + ge];
  float v = h1[(size_t)s*NFC + c] * W[(size_t)e*NFC + c];
  atomicAdd(&agg[(size_t)d*NFC + c], v);
}

// hsum[e, c] = h[src[e0+e], c] + h[dst[e0+e], c]  for e in [0, ce)
__global__ void hsum_kernel(const int* __restrict__ ei, int e0, int ce,
                            const float* __restrict__ h, float* __restrict__ hsum) {
  int idx = blockIdx.x * blockDim.x + threadIdx.x;
  if (idx >= ce * HC) return;
  int e = idx >> 7, c = idx & 127;
  int ge = e0 + e;
  int s = ei[ge];
  int d = ei[N_EDGES + ge];
  hsum[idx] = h[(size_t)s*HC + c] + h[(size_t)d*HC + c];
}

// ssum[batch[n], c] += h[n, c];  cnt[batch[n]] += 1
__global__ void pool_kernel(const int* __restrict__ batch, const float* __restrict__ h,
                            float* __restrict__ ssum, float* __restrict__ cnt) {
  int idx = blockIdx.x * blockDim.x + threadIdx.x;
  if (idx >= N_NODES * HC) return;
  int n = idx >> 7, c = idx & 127;
  int b = batch[n];
  atomicAdd(&ssum[(size_t)b*HC + c], h[idx]);
  if (c == 0) atomicAdd(&cnt[b], 1.0f);
}

// y[g] = gelu(g_row @ w1.T + b1) @ w2.T + b2, g_row = ssum[g]/max(cnt[g],1)
__global__ __launch_bounds__(256) void head_kernel(
    const float* __restrict__ ssum, const float* __restrict__ cnt,
    const float* __restrict__ w1, const float* __restrict__ b1,
    const float* __restrict__ w2, const float* __restrict__ b2,
    float* __restrict__ y) {
  int g = blockIdx.x;
  __shared__ float gs[HC];
  __shared__ float red[256];
  int tid = threadIdx.x;
  float inv = 1.0f / fmaxf(cnt[g], 1.0f);
  if (tid < HC) gs[tid] = ssum[(size_t)g*HC + tid] * inv;
  __syncthreads();
  float partial = 0.0f;
  for (int f = tid; f < NFFC; f += 256) {
    float acc = b1[f];
    const float* wr = w1 + (size_t)f*HC;
#pragma unroll 8
    for (int k=0;k<HC;k++) acc = fmaf(gs[k], wr[k], acc);
    float t = 0.5f * acc * (1.0f + erff(acc * 0.70710678118654752440f)); // exact GELU
    partial = fmaf(t, w2[f], partial);
  }
  red[tid] = partial;
  __syncthreads();
  for (int s = 128; s > 0; s >>= 1) {
    if (tid < s) red[tid] += red[tid + s];
    __syncthreads();
  }
  if (tid == 0) y[g] = red[0] + b2[0];
}

// ---------------------------------------------------------------------------
extern "C" void kernel_launch(void* const* d_in, const int* in_sizes, int n_in,
                              void* d_out, int out_size, void* d_ws, size_t ws_size,
                              hipStream_t stream) {
  const int*   x     = (const int*)  d_in[0];
  const int*   ei    = (const int*)  d_in[1];
  const float* eattr = (const float*)d_in[2];
  const int*   batch = (const int*)  d_in[3];
  const float* pos   = (const float*)d_in[4];
  const float* vert  = (const float*)d_in[5];
  const float* posw  = (const float*)d_in[6];
  const float* edgew = (const float*)d_in[7];
  const float* fw1   = (const float*)d_in[8];
  const float* fb1   = (const float*)d_in[9];
  const float* fw2   = (const float*)d_in[10];
  const float* fb2   = (const float*)d_in[11];
  const float* l1w   = (const float*)d_in[12];
  const float* l2w   = (const float*)d_in[13];
  const float* l2b   = (const float*)d_in[14];
  const float* l3w   = (const float*)d_in[15];
  const float* l3b   = (const float*)d_in[16];
  const float* emw   = (const float*)d_in[17];
  const float* emb   = (const float*)d_in[18];
  const float* hw1   = (const float*)d_in[19];
  const float* hb1   = (const float*)d_in[20];
  const float* hw2   = (const float*)d_in[21];
  const float* hb2   = (const float*)d_in[22];
  float* out = (float*)d_out;

  // ---- adaptive workspace layout (ws_size-aware; persistent floor ~231 MB) ----
  char* ws = (char*)d_ws;
  size_t off = 0;
  auto alloc = [&](size_t bytes) { char* p = ws + off; off += (bytes + 511) & ~(size_t)511; return p; };
  float* ea   = (float*)alloc((size_t)N_EDGES*HC*4);    // 102.4 MB persistent
  float* h    = (float*)alloc((size_t)N_NODES*HC*4);    //  25.6 MB persistent
  float* h1   = (float*)alloc((size_t)N_NODES*NFC*4);   //  51.2 MB (lin1 out; reused as t2)
  float* agg  = (float*)alloc((size_t)N_NODES*NFC*4);   //  51.2 MB
  float* ssum = (float*)alloc((size_t)N_GRAPH*HC*4);
  float* cnt  = (float*)alloc((size_t)N_GRAPH*4);
  // remaining space -> two chunked edge-space temporaries of CE x NFC each
  size_t avail = (ws_size > off + 4096) ? (ws_size - off - 4096) : 0;
  long long ce_ll = (long long)(avail / (2ull * NFC * 4));
  int CE = (int)((ce_ll / 64) * 64);
  if (CE > N_EDGES) CE = N_EDGES;
  if (CE < 64) CE = 64;  // nothing sane possible below this; best effort
  float* t1c = (float*)alloc((size_t)CE*NFC*4);   // filter tmp; reused as hsum chunk
  float* Wfc = (float*)alloc((size_t)CE*NFC*4);   // per-edge filter W chunk

  const int GN = (N_NODES + 63) / 64;          // 782

  embed_kernel<<<N_NODES, 128, 0, stream>>>(x, pos, vert, posw, h);
  edgeproj_kernel<<<(N_EDGES*HC + 255)/256, 256, 0, stream>>>(eattr, edgew, ea);

  for (int i = 0; i < NLAYER; ++i) {
    // h1 = h @ l1w.T                                 [N,256]
    gemm_kernel<EPI_NONE><<<dim3(GN,2), 256, 0, stream>>>(
        h, nullptr, HC, l1w + (size_t)i*NFC*HC, nullptr, nullptr, h1,
        N_NODES, HC, NFC);
    // agg = 0
    zero_kernel<<<((N_NODES*NFC/4) + 255)/256, 256, 0, stream>>>(
        (float4*)agg, N_NODES*NFC/4);
    // filter MLP + scatter, chunked over edges
    for (int e0 = 0; e0 < N_EDGES; e0 += CE) {
      int ce = (N_EDGES - e0 < CE) ? (N_EDGES - e0) : CE;
      int ge = (ce + 63) / 64;
      // t1c = ssp(ea_chunk @ fw1.T + fb1)            [ce,256]
      gemm_kernel<EPI_SSP><<<dim3(ge,2), 256, 0, stream>>>(
          ea + (size_t)e0*HC, nullptr, HC, fw1 + (size_t)i*NFC*HC,
          fb1 + (size_t)i*NFC, nullptr, t1c, ce, HC, NFC);
      // Wfc = t1c @ fw2.T + fb2                      [ce,256]
      gemm_kernel<EPI_BIAS><<<dim3(ge,2), 256, 0, stream>>>(
          t1c, nullptr, NFC, fw2 + (size_t)i*NFC*NFC,
          fb2 + (size_t)i*NFC, nullptr, Wfc, ce, NFC, NFC);
      // agg[dst] += h1[src] * Wfc
      scatter_kernel<<<ce, NFC, 0, stream>>>(ei, e0, h1, Wfc, agg);
    }
    // t2(=h1) = ssp(agg @ l2w.T + l2b)               [N,128]
    gemm_kernel<EPI_SSP><<<dim3(GN,1), 256, 0, stream>>>(
        agg, nullptr, NFC, l2w + (size_t)i*HC*NFC, l2b + (size_t)i*HC, nullptr, h1,
        N_NODES, NFC, HC);
    // h = relu(t2 @ l3w.T + l3b) + h   (in place; per-block rows disjoint)
    gemm_kernel<EPI_RELU_RES><<<dim3(GN,1), 256, 0, stream>>>(
        h1, nullptr, HC, l3w + (size_t)i*HC*HC, l3b + (size_t)i*HC, h, h,
        N_NODES, HC, HC);
    // edge MLP update, chunked: ea = tanh(cat(ea, h[src]+h[dst]) @ emw.T + emb) + ea
    for (int e0 = 0; e0 < N_EDGES; e0 += CE) {
      int ce = (N_EDGES - e0 < CE) ? (N_EDGES - e0) : CE;
      int ge = (ce + 63) / 64;
      hsum_kernel<<<(ce*HC + 255)/256, 256, 0, stream>>>(ei, e0, ce, h, t1c);
      gemm_kernel<EPI_TANH_RES><<<dim3(ge,1), 256, 0, stream>>>(
          ea + (size_t)e0*HC, t1c, HC, emw + (size_t)i*HC*2*HC,
          emb + (size_t)i*HC, ea + (size_t)e0*HC, ea + (size_t)e0*HC,
          ce, 2*HC, HC);
    }
  }

  zero_kernel<<<((N_GRAPH*HC/4) + 255)/256, 256, 0, stream>>>((float4*)ssum, N_GRAPH*HC/4);
  zero_kernel<<<((N_GRAPH/4) + 255)/256, 256, 0, stream>>>((float4*)cnt, N_GRAPH/4);
  pool_kernel<<<(N_NODES*HC + 255)/256, 256, 0, stream>>>(batch, h, ssum, cnt);
  head_kernel<<<N_GRAPH, 256, 0, stream>>>(ssum, cnt, hw1, hb1, hw2, hb2, out);
}

// Round 3
// 5293.377 us; speedup vs baseline: 1.6637x; 1.6637x over previous
//
#include <hip/hip_runtime.h>
#include <hip/hip_bf16.h>
#include <math.h>

#define N_NODES 50000
#define N_EDGES 200000
#define N_GRAPH 1024
#define HC      128
#define NFC     256
#define NLAYER  5
#define NFFC    512

enum { EPI_NONE=0, EPI_SCATTER=1, EPI_SSP=2, EPI_RELU_RES=3, EPI_TANH_RES=4 };

typedef short bf16x8 __attribute__((ext_vector_type(8)));
typedef float f4v    __attribute__((ext_vector_type(4)));

__device__ __forceinline__ float ssp_f(float x) {
  return fmaxf(x, 0.0f) + log1pf(expf(-fabsf(x))) - 0.69314718055994530942f;
}
__device__ __forceinline__ unsigned short f2bf(float x) {
  union { float f; unsigned u; } v; v.f = x;
  unsigned r = v.u + 0x7fff + ((v.u >> 16) & 1);
  return (unsigned short)(r >> 16);
}
__device__ __forceinline__ float bf2f(unsigned short b) {
  union { unsigned u; float f; } v; v.u = (unsigned)b << 16; return v.f;
}

// ---------------------------------------------------------------------------
__global__ void zero_kernel(float4* __restrict__ p, int n4) {
  int i = blockIdx.x * blockDim.x + threadIdx.x;
  if (i < n4) p[i] = make_float4(0.f, 0.f, 0.f, 0.f);
}

__global__ void embed_kernel(const int* __restrict__ x, const float* __restrict__ pos,
                             const float* __restrict__ vert, const float* __restrict__ posw,
                             float* __restrict__ h) {
  int n = blockIdx.x;
  int c = threadIdx.x;            // 128 threads
  float v;
  if (c < 80) {
    v = vert[(size_t)x[n] * 80 + c];
  } else {
    int j = c - 80;
    v = pos[n*3+0]*posw[j*3+0] + pos[n*3+1]*posw[j*3+1] + pos[n*3+2]*posw[j*3+2];
  }
  h[(size_t)n*HC + c] = v;
}

__global__ void edgeproj_kernel(const float* __restrict__ eattr, const float* __restrict__ ew,
                                float* __restrict__ ea) {
  int idx = blockIdx.x * blockDim.x + threadIdx.x;
  if (idx >= N_EDGES * HC) return;
  int e = idx >> 7, c = idx & 127;
  const float* a = eattr + (size_t)e*4;
  const float* w = ew + (size_t)c*4;
  ea[idx] = a[0]*w[0] + a[1]*w[1] + a[2]*w[2] + a[3]*w[3];
}

// ---------------------------------------------------------------------------
// Split-bf16 MFMA GEMM: C[M,N] = epi(A @ Bw^T + bias) (+resid / scatter).
// Each fp32 operand -> hi+lo bf16; acc += ah*bh + ah*bl + al*bh (3 MFMAs).
// Tile 128x128, BK=32, 256 threads (4 waves in 2x2, each 64x64 = 4x4 MFMA tiles).
// GATHER=1: A = cat(A0[.,0:128], h[src]+h[dst]) with K=256.
// EPI_SCATTER: atomicAdd(agg[dst[e]*256+c], (acc+bias)*h1[src[e]*256+c]).
template<int EPI, int GATHER>
__global__ __launch_bounds__(256, 2) void mgemm(
    const float* A0, const float* __restrict__ Bw, const float* __restrict__ bias,
    const float* resid, float* C, int M, int K, int N,
    const int* __restrict__ ei, int e0, const float* __restrict__ hgat,
    const float* __restrict__ h1, float* agg)
{
  // LDS: Ah,Al,Bh,Bl each 128 rows x 40 ushort pitch (32 used + 8 pad)
  __shared__ unsigned short lds[4 * 128 * 40];     // 40 KiB
  __shared__ int sS[128], sD[128];
  const int AH = 0, AL = 5120, BH = 10240, BL = 15360;

  const int tid  = threadIdx.x;
  const int m0   = blockIdx.x * 128;
  const int n0   = blockIdx.y * 128;
  const int lane = tid & 63, wave = tid >> 6;
  const int quad = lane >> 4, l16 = lane & 15;
  const int wm = (wave >> 1) * 64, wn = (wave & 1) * 64;
  const int r  = tid >> 1;           // staging row 0..127
  const int c0 = (tid & 1) * 16;     // staging col offset 0/16

  if (EPI == EPI_SCATTER || GATHER) {
    if (tid < 128) {
      int e  = m0 + tid;
      int ge = (e < M) ? (e0 + e) : e0;
      sS[tid] = ei[ge];
      sD[tid] = ei[N_EDGES + ge];
    }
  }

  f4v acc[4][4];
  const f4v zf = {0.f, 0.f, 0.f, 0.f};
#pragma unroll
  for (int i = 0; i < 4; i++)
#pragma unroll
    for (int j = 0; j < 4; j++) acc[i][j] = zf;

  const bool mok = (m0 + r) < M;
  const size_t arow = (size_t)(m0 + r);
  const size_t brow = (size_t)(n0 + r);

  __syncthreads();   // sS/sD visible

  for (int kk = 0; kk < K; kk += 32) {
    float av[16], bv[16];
    const int kg = kk + c0;
    if (!GATHER) {
      if (mok) {
        const float* ap = A0 + arow * K + kg;
#pragma unroll
        for (int q = 0; q < 4; q++) *(float4*)&av[q*4] = *(const float4*)(ap + q*4);
      } else {
#pragma unroll
        for (int j = 0; j < 16; j++) av[j] = 0.f;
      }
    } else {
      if (mok) {
        if (kg < HC) {
          const float* ap = A0 + arow * HC + kg;
#pragma unroll
          for (int q = 0; q < 4; q++) *(float4*)&av[q*4] = *(const float4*)(ap + q*4);
        } else {
          const float* p1 = hgat + (size_t)sS[r] * HC + (kg - HC);
          const float* p2 = hgat + (size_t)sD[r] * HC + (kg - HC);
#pragma unroll
          for (int q = 0; q < 4; q++) {
            float4 xa = *(const float4*)(p1 + q*4);
            float4 xb = *(const float4*)(p2 + q*4);
            av[q*4+0] = xa.x + xb.x; av[q*4+1] = xa.y + xb.y;
            av[q*4+2] = xa.z + xb.z; av[q*4+3] = xa.w + xb.w;
          }
        }
      } else {
#pragma unroll
        for (int j = 0; j < 16; j++) av[j] = 0.f;
      }
    }
    {
      const float* bp = Bw + brow * K + kg;
#pragma unroll
      for (int q = 0; q < 4; q++) *(float4*)&bv[q*4] = *(const float4*)(bp + q*4);
    }

    __syncthreads();   // previous iteration's LDS reads complete

    unsigned short th[16], tl[16];
#pragma unroll
    for (int j = 0; j < 16; j++) {
      unsigned short hb = f2bf(av[j]);
      th[j] = hb; tl[j] = f2bf(av[j] - bf2f(hb));
    }
    *(bf16x8*)&lds[AH + r*40 + c0]     = *(bf16x8*)&th[0];
    *(bf16x8*)&lds[AH + r*40 + c0 + 8] = *(bf16x8*)&th[8];
    *(bf16x8*)&lds[AL + r*40 + c0]     = *(bf16x8*)&tl[0];
    *(bf16x8*)&lds[AL + r*40 + c0 + 8] = *(bf16x8*)&tl[8];
#pragma unroll
    for (int j = 0; j < 16; j++) {
      unsigned short hb = f2bf(bv[j]);
      th[j] = hb; tl[j] = f2bf(bv[j] - bf2f(hb));
    }
    *(bf16x8*)&lds[BH + r*40 + c0]     = *(bf16x8*)&th[0];
    *(bf16x8*)&lds[BH + r*40 + c0 + 8] = *(bf16x8*)&th[8];
    *(bf16x8*)&lds[BL + r*40 + c0]     = *(bf16x8*)&tl[0];
    *(bf16x8*)&lds[BL + r*40 + c0 + 8] = *(bf16x8*)&tl[8];

    __syncthreads();

    bf16x8 ah[4], al[4], bh[4], bl[4];
#pragma unroll
    for (int t = 0; t < 4; t++) {
      const int ra = (wm + t*16 + l16) * 40 + quad * 8;
      const int rb = (wn + t*16 + l16) * 40 + quad * 8;
      ah[t] = *(const bf16x8*)&lds[AH + ra];
      al[t] = *(const bf16x8*)&lds[AL + ra];
      bh[t] = *(const bf16x8*)&lds[BH + rb];
      bl[t] = *(const bf16x8*)&lds[BL + rb];
    }
#pragma unroll
    for (int mt = 0; mt < 4; mt++)
#pragma unroll
      for (int nt = 0; nt < 4; nt++) {
        acc[mt][nt] = __builtin_amdgcn_mfma_f32_16x16x32_bf16(ah[mt], bh[nt], acc[mt][nt], 0, 0, 0);
        acc[mt][nt] = __builtin_amdgcn_mfma_f32_16x16x32_bf16(ah[mt], bl[nt], acc[mt][nt], 0, 0, 0);
        acc[mt][nt] = __builtin_amdgcn_mfma_f32_16x16x32_bf16(al[mt], bh[nt], acc[mt][nt], 0, 0, 0);
      }
  }

  // epilogue: C/D layout col = lane&15, row = quad*4 + reg
#pragma unroll
  for (int nt = 0; nt < 4; nt++) {
    const int ncol = n0 + wn + nt*16 + l16;
    float bz = 0.f;
    if constexpr (EPI != EPI_NONE) bz = bias[ncol];
#pragma unroll
    for (int mt = 0; mt < 4; mt++) {
      const int mb = wm + mt*16 + quad*4;
#pragma unroll
      for (int rr = 0; rr < 4; rr++) {
        const int ml = mb + rr;
        const int m  = m0 + ml;
        if (m >= M) continue;
        float v = acc[mt][nt][rr] + bz;
        if constexpr (EPI == EPI_SSP)           v = ssp_f(v);
        else if constexpr (EPI == EPI_RELU_RES) v = fmaxf(v, 0.f);
        else if constexpr (EPI == EPI_TANH_RES) v = tanhf(v);
        if constexpr (EPI == EPI_SCATTER) {
          const int s = sS[ml], d = sD[ml];
          const float g = h1[(size_t)s * NFC + ncol];
          atomicAdd(&agg[(size_t)d * NFC + ncol], v * g);
        } else {
          if constexpr (EPI == EPI_RELU_RES || EPI == EPI_TANH_RES)
            v += resid[(size_t)m * N + ncol];
          C[(size_t)m * N + ncol] = v;
        }
      }
    }
  }
}

// ---------------------------------------------------------------------------
__global__ void pool_kernel(const int* __restrict__ batch, const float* __restrict__ h,
                            float* __restrict__ ssum, float* __restrict__ cnt) {
  int idx = blockIdx.x * blockDim.x + threadIdx.x;
  if (idx >= N_NODES * HC) return;
  int n = idx >> 7, c = idx & 127;
  int b = batch[n];
  atomicAdd(&ssum[(size_t)b*HC + c], h[idx]);
  if (c == 0) atomicAdd(&cnt[b], 1.0f);
}

__global__ __launch_bounds__(256) void head_kernel(
    const float* __restrict__ ssum, const float* __restrict__ cnt,
    const float* __restrict__ w1, const float* __restrict__ b1,
    const float* __restrict__ w2, const float* __restrict__ b2,
    float* __restrict__ y) {
  int g = blockIdx.x;
  __shared__ float gs[HC];
  __shared__ float red[256];
  int tid = threadIdx.x;
  float inv = 1.0f / fmaxf(cnt[g], 1.0f);
  if (tid < HC) gs[tid] = ssum[(size_t)g*HC + tid] * inv;
  __syncthreads();
  float partial = 0.0f;
  for (int f = tid; f < NFFC; f += 256) {
    float acc = b1[f];
    const float* wr = w1 + (size_t)f*HC;
#pragma unroll 8
    for (int k = 0; k < HC; k++) acc = fmaf(gs[k], wr[k], acc);
    float t = 0.5f * acc * (1.0f + erff(acc * 0.70710678118654752440f));
    partial = fmaf(t, w2[f], partial);
  }
  red[tid] = partial;
  __syncthreads();
  for (int s = 128; s > 0; s >>= 1) {
    if (tid < s) red[tid] += red[tid + s];
    __syncthreads();
  }
  if (tid == 0) y[g] = red[0] + b2[0];
}

// ---------------------------------------------------------------------------
extern "C" void kernel_launch(void* const* d_in, const int* in_sizes, int n_in,
                              void* d_out, int out_size, void* d_ws, size_t ws_size,
                              hipStream_t stream) {
  const int*   x     = (const int*)  d_in[0];
  const int*   ei    = (const int*)  d_in[1];
  const float* eattr = (const float*)d_in[2];
  const int*   batch = (const int*)  d_in[3];
  const float* pos   = (const float*)d_in[4];
  const float* vert  = (const float*)d_in[5];
  const float* posw  = (const float*)d_in[6];
  const float* edgew = (const float*)d_in[7];
  const float* fw1   = (const float*)d_in[8];
  const float* fb1   = (const float*)d_in[9];
  const float* fw2   = (const float*)d_in[10];
  const float* fb2   = (const float*)d_in[11];
  const float* l1w   = (const float*)d_in[12];
  const float* l2w   = (const float*)d_in[13];
  const float* l2b   = (const float*)d_in[14];
  const float* l3w   = (const float*)d_in[15];
  const float* l3b   = (const float*)d_in[16];
  const float* emw   = (const float*)d_in[17];
  const float* emb   = (const float*)d_in[18];
  const float* hw1   = (const float*)d_in[19];
  const float* hb1   = (const float*)d_in[20];
  const float* hw2   = (const float*)d_in[21];
  const float* hb2   = (const float*)d_in[22];
  float* out = (float*)d_out;

  char* ws = (char*)d_ws;
  size_t off = 0;
  auto alloc = [&](size_t bytes) { char* p = ws + off; off += (bytes + 511) & ~(size_t)511; return p; };
  float* ea   = (float*)alloc((size_t)N_EDGES*HC*4);    // 102.4 MB persistent
  float* h    = (float*)alloc((size_t)N_NODES*HC*4);    //  25.6 MB persistent
  float* h1   = (float*)alloc((size_t)N_NODES*NFC*4);   //  51.2 MB (lin1 out / t2)
  float* agg  = (float*)alloc((size_t)N_NODES*NFC*4);   //  51.2 MB
  float* ssum = (float*)alloc((size_t)N_GRAPH*HC*4);
  float* cnt  = (float*)alloc((size_t)N_GRAPH*4);
  // remaining -> one chunked edge-space temp (filter GEMM1 output)
  size_t avail = (ws_size > off + 4096) ? (ws_size - off - 4096) : 0;
  long long ce_ll = (long long)(avail / ((size_t)NFC * 4));
  int CE = (int)((ce_ll / 128) * 128);
  if (CE > N_EDGES) CE = N_EDGES;
  if (CE < 128) CE = 128;
  float* t1c = (float*)alloc((size_t)CE*NFC*4);

  const int GN = (N_NODES + 127) / 128;   // 391
  const int GE = (N_EDGES + 127) / 128;   // 1563

  embed_kernel<<<N_NODES, 128, 0, stream>>>(x, pos, vert, posw, h);
  edgeproj_kernel<<<(N_EDGES*HC + 255)/256, 256, 0, stream>>>(eattr, edgew, ea);

  for (int i = 0; i < NLAYER; ++i) {
    // h1 = h @ l1w.T                        [N,256]
    mgemm<EPI_NONE,0><<<dim3(GN,2), 256, 0, stream>>>(
        h, l1w + (size_t)i*NFC*HC, nullptr, nullptr, h1,
        N_NODES, HC, NFC, nullptr, 0, nullptr, nullptr, nullptr);
    zero_kernel<<<((N_NODES*NFC/4) + 255)/256, 256, 0, stream>>>(
        (float4*)agg, N_NODES*NFC/4);
    // filter MLP + fused scatter, chunked over edges
    for (int e0 = 0; e0 < N_EDGES; e0 += CE) {
      int ce = (N_EDGES - e0 < CE) ? (N_EDGES - e0) : CE;
      int gc = (ce + 127) / 128;
      // t1c = ssp(ea_chunk @ fw1.T + fb1)   [ce,256]
      mgemm<EPI_SSP,0><<<dim3(gc,2), 256, 0, stream>>>(
          ea + (size_t)e0*HC, fw1 + (size_t)i*NFC*HC, fb1 + (size_t)i*NFC,
          nullptr, t1c, ce, HC, NFC, nullptr, 0, nullptr, nullptr, nullptr);
      // agg[dst] += (t1c @ fw2.T + fb2) * h1[src]   (fused scatter)
      mgemm<EPI_SCATTER,0><<<dim3(gc,2), 256, 0, stream>>>(
          t1c, fw2 + (size_t)i*NFC*NFC, fb2 + (size_t)i*NFC,
          nullptr, nullptr, ce, NFC, NFC, ei, e0, nullptr, h1, agg);
    }
    // t2(=h1) = ssp(agg @ l2w.T + l2b)      [N,128]
    mgemm<EPI_SSP,0><<<dim3(GN,1), 256, 0, stream>>>(
        agg, l2w + (size_t)i*HC*NFC, l2b + (size_t)i*HC, nullptr, h1,
        N_NODES, NFC, HC, nullptr, 0, nullptr, nullptr, nullptr);
    // h = relu(t2 @ l3w.T + l3b) + h        (in place; rows disjoint per block)
    mgemm<EPI_RELU_RES,0><<<dim3(GN,1), 256, 0, stream>>>(
        h1, l3w + (size_t)i*HC*HC, l3b + (size_t)i*HC, h, h,
        N_NODES, HC, HC, nullptr, 0, nullptr, nullptr, nullptr);
    // ea = tanh(cat(ea, h[src]+h[dst]) @ emw.T + emb) + ea  (gather fused)
    mgemm<EPI_TANH_RES,1><<<dim3(GE,1), 256, 0, stream>>>(
        ea, emw + (size_t)i*HC*2*HC, emb + (size_t)i*HC, ea, ea,
        N_EDGES, 2*HC, HC, ei, 0, h, nullptr, nullptr);
  }

  zero_kernel<<<((N_GRAPH*HC/4) + 255)/256, 256, 0, stream>>>((float4*)ssum, N_GRAPH*HC/4);
  zero_kernel<<<((N_GRAPH/4) + 255)/256, 256, 0, stream>>>((float4*)cnt, N_GRAPH/4);
  pool_kernel<<<(N_NODES*HC + 255)/256, 256, 0, stream>>>(batch, h, ssum, cnt);
  head_kernel<<<N_GRAPH, 256, 0, stream>>>(ssum, cnt, hw1, hb1, hw2, hb2, out);
}

// Round 4
// 4700.851 us; speedup vs baseline: 1.8734x; 1.1260x over previous
//
#include <hip/hip_runtime.h>
#include <hip/hip_bf16.h>
#include <math.h>

#define N_NODES 50000
#define N_EDGES 200000
#define N_GRAPH 1024
#define HC      128
#define NFC     256
#define NLAYER  5
#define NFFC    512

enum { EPI_NONE=0, EPI_SSP=2, EPI_RELU_RES=3, EPI_TANH_RES=4 };

typedef short bf16x8 __attribute__((ext_vector_type(8)));
typedef float f4v    __attribute__((ext_vector_type(4)));

__device__ __forceinline__ float ssp_f(float x) {
  return fmaxf(x, 0.0f) + log1pf(expf(-fabsf(x))) - 0.69314718055994530942f;
}
__device__ __forceinline__ unsigned short f2bf(float x) {
  union { float f; unsigned u; } v; v.f = x;
  unsigned r = v.u + 0x7fff + ((v.u >> 16) & 1);
  return (unsigned short)(r >> 16);
}
__device__ __forceinline__ float bf2f(unsigned short b) {
  union { unsigned u; float f; } v; v.u = (unsigned)b << 16; return v.f;
}

// ---------------------------------------------------------------------------
__global__ void zero_kernel(float4* __restrict__ p, int n4) {
  int i = blockIdx.x * blockDim.x + threadIdx.x;
  if (i < n4) p[i] = make_float4(0.f, 0.f, 0.f, 0.f);
}

__global__ void embed_kernel(const int* __restrict__ x, const float* __restrict__ pos,
                             const float* __restrict__ vert, const float* __restrict__ posw,
                             float* __restrict__ h) {
  int n = blockIdx.x;
  int c = threadIdx.x;            // 128 threads
  float v;
  if (c < 80) {
    v = vert[(size_t)x[n] * 80 + c];
  } else {
    int j = c - 80;
    v = pos[n*3+0]*posw[j*3+0] + pos[n*3+1]*posw[j*3+1] + pos[n*3+2]*posw[j*3+2];
  }
  h[(size_t)n*HC + c] = v;
}

__global__ void edgeproj_kernel(const float* __restrict__ eattr, const float* __restrict__ ew,
                                float* __restrict__ ea) {
  int idx = blockIdx.x * blockDim.x + threadIdx.x;
  if (idx >= N_EDGES * HC) return;
  int e = idx >> 7, c = idx & 127;
  const float* a = eattr + (size_t)e*4;
  const float* w = ew + (size_t)c*4;
  ea[idx] = a[0]*w[0] + a[1]*w[1] + a[2]*w[2] + a[3]*w[3];
}

// ---------------------------------------------------------------------------
// Split-bf16 MFMA GEMM (generic): C[M,N] = epi(A @ Bw^T + bias) (+resid).
// Tile 128x128, BK=32, 256 threads. GATHER=1: A = cat(A0, h[src]+h[dst]), K=256.
template<int EPI, int GATHER>
__global__ __launch_bounds__(256, 2) void mgemm(
    const float* A0, const float* __restrict__ Bw, const float* __restrict__ bias,
    const float* resid, float* C, int M, int K, int N,
    const int* __restrict__ ei, const float* __restrict__ hgat)
{
  __shared__ unsigned short lds[4 * 128 * 40];     // Ah,Al,Bh,Bl: 40 KiB
  __shared__ int sS[128], sD[128];
  const int AH = 0, AL = 5120, BH = 10240, BL = 15360;

  const int tid  = threadIdx.x;
  const int m0   = blockIdx.x * 128;
  const int n0   = blockIdx.y * 128;
  const int lane = tid & 63, wave = tid >> 6;
  const int quad = lane >> 4, l16 = lane & 15;
  const int wm = (wave >> 1) * 64, wn = (wave & 1) * 64;
  const int r  = tid >> 1;
  const int c0 = (tid & 1) * 16;

  if (GATHER) {
    if (tid < 128) {
      int e  = m0 + tid;
      int ge = (e < M) ? e : (M - 1);
      sS[tid] = ei[ge];
      sD[tid] = ei[N_EDGES + ge];
    }
  }

  f4v acc[4][4];
  const f4v zf = {0.f, 0.f, 0.f, 0.f};
#pragma unroll
  for (int i = 0; i < 4; i++)
#pragma unroll
    for (int j = 0; j < 4; j++) acc[i][j] = zf;

  const bool mok = (m0 + r) < M;
  const size_t arow = (size_t)(m0 + r);
  const size_t brow = (size_t)(n0 + r);

  __syncthreads();

  for (int kk = 0; kk < K; kk += 32) {
    float av[16], bv[16];
    const int kg = kk + c0;
    if (!GATHER) {
      if (mok) {
        const float* ap = A0 + arow * K + kg;
#pragma unroll
        for (int q = 0; q < 4; q++) *(float4*)&av[q*4] = *(const float4*)(ap + q*4);
      } else {
#pragma unroll
        for (int j = 0; j < 16; j++) av[j] = 0.f;
      }
    } else {
      if (mok) {
        if (kg < HC) {
          const float* ap = A0 + arow * HC + kg;
#pragma unroll
          for (int q = 0; q < 4; q++) *(float4*)&av[q*4] = *(const float4*)(ap + q*4);
        } else {
          const float* p1 = hgat + (size_t)sS[r] * HC + (kg - HC);
          const float* p2 = hgat + (size_t)sD[r] * HC + (kg - HC);
#pragma unroll
          for (int q = 0; q < 4; q++) {
            float4 xa = *(const float4*)(p1 + q*4);
            float4 xb = *(const float4*)(p2 + q*4);
            av[q*4+0] = xa.x + xb.x; av[q*4+1] = xa.y + xb.y;
            av[q*4+2] = xa.z + xb.z; av[q*4+3] = xa.w + xb.w;
          }
        }
      } else {
#pragma unroll
        for (int j = 0; j < 16; j++) av[j] = 0.f;
      }
    }
    {
      const float* bp = Bw + brow * K + kg;
#pragma unroll
      for (int q = 0; q < 4; q++) *(float4*)&bv[q*4] = *(const float4*)(bp + q*4);
    }

    __syncthreads();

    unsigned short th[16], tl[16];
#pragma unroll
    for (int j = 0; j < 16; j++) {
      unsigned short hb = f2bf(av[j]);
      th[j] = hb; tl[j] = f2bf(av[j] - bf2f(hb));
    }
    *(bf16x8*)&lds[AH + r*40 + c0]     = *(bf16x8*)&th[0];
    *(bf16x8*)&lds[AH + r*40 + c0 + 8] = *(bf16x8*)&th[8];
    *(bf16x8*)&lds[AL + r*40 + c0]     = *(bf16x8*)&tl[0];
    *(bf16x8*)&lds[AL + r*40 + c0 + 8] = *(bf16x8*)&tl[8];
#pragma unroll
    for (int j = 0; j < 16; j++) {
      unsigned short hb = f2bf(bv[j]);
      th[j] = hb; tl[j] = f2bf(bv[j] - bf2f(hb));
    }
    *(bf16x8*)&lds[BH + r*40 + c0]     = *(bf16x8*)&th[0];
    *(bf16x8*)&lds[BH + r*40 + c0 + 8] = *(bf16x8*)&th[8];
    *(bf16x8*)&lds[BL + r*40 + c0]     = *(bf16x8*)&tl[0];
    *(bf16x8*)&lds[BL + r*40 + c0 + 8] = *(bf16x8*)&tl[8];

    __syncthreads();

    bf16x8 ah[4], al[4], bh[4], bl[4];
#pragma unroll
    for (int t = 0; t < 4; t++) {
      const int ra = (wm + t*16 + l16) * 40 + quad * 8;
      const int rb = (wn + t*16 + l16) * 40 + quad * 8;
      ah[t] = *(const bf16x8*)&lds[AH + ra];
      al[t] = *(const bf16x8*)&lds[AL + ra];
      bh[t] = *(const bf16x8*)&lds[BH + rb];
      bl[t] = *(const bf16x8*)&lds[BL + rb];
    }
#pragma unroll
    for (int mt = 0; mt < 4; mt++)
#pragma unroll
      for (int nt = 0; nt < 4; nt++) {
        acc[mt][nt] = __builtin_amdgcn_mfma_f32_16x16x32_bf16(ah[mt], bh[nt], acc[mt][nt], 0, 0, 0);
        acc[mt][nt] = __builtin_amdgcn_mfma_f32_16x16x32_bf16(ah[mt], bl[nt], acc[mt][nt], 0, 0, 0);
        acc[mt][nt] = __builtin_amdgcn_mfma_f32_16x16x32_bf16(al[mt], bh[nt], acc[mt][nt], 0, 0, 0);
      }
  }

#pragma unroll
  for (int nt = 0; nt < 4; nt++) {
    const int ncol = n0 + wn + nt*16 + l16;
    float bz = 0.f;
    if constexpr (EPI != EPI_NONE) bz = bias[ncol];
#pragma unroll
    for (int mt = 0; mt < 4; mt++) {
      const int mb = wm + mt*16 + quad*4;
#pragma unroll
      for (int rr = 0; rr < 4; rr++) {
        const int m = m0 + mb + rr;
        if (m >= M) continue;
        float v = acc[mt][nt][rr] + bz;
        if constexpr (EPI == EPI_SSP)           v = ssp_f(v);
        else if constexpr (EPI == EPI_RELU_RES) v = fmaxf(v, 0.f);
        else if constexpr (EPI == EPI_TANH_RES) v = tanhf(v);
        if constexpr (EPI == EPI_RELU_RES || EPI == EPI_TANH_RES)
          v += resid[(size_t)m * N + ncol];
        C[(size_t)m * N + ncol] = v;
      }
    }
  }
}

// ---------------------------------------------------------------------------
// Fused filter MLP + scatter: per block of 128 edges,
//   T = ssp(ea_tile @ fw1^T + fb1)                      [128,256] (LDS only)
//   W = T @ fw2^T + fb2                                 [128,256] (regs)
//   agg[dst[e],c] += W[e,c] * h1[src[e],c]              (atomic epilogue)
// 512 threads = 8 waves; LDS ~148 KB -> 1 block/CU, 2 waves/SIMD.
__global__ __launch_bounds__(512, 1) void ffs_kernel(
    const float* __restrict__ ea, const float* __restrict__ fw1,
    const float* __restrict__ fb1, const float* __restrict__ fw2,
    const float* __restrict__ fb2, const int* __restrict__ ei,
    const float* __restrict__ h1, float* agg)
{
  __shared__ unsigned short ldsA[2][128][136];   // ea hi/lo (k pitch 136)
  __shared__ unsigned short ldsB[20480];         // union: B1 64x136 x2 | B2 256x40 x2
  __shared__ unsigned short ldsT[2][128][72];    // T chunk hi/lo (64 cols)
  __shared__ int sS[128], sD[128];

  const int tid  = threadIdx.x;
  const int m0   = blockIdx.x * 128;
  const int lane = tid & 63, wave = tid >> 6;     // wave 0..7
  const int quad = lane >> 4, l16 = lane & 15;

  // stage ea tile: row r = tid>>2, cols (tid&3)*32 .. +32
  {
    const int r = tid >> 2, cb = (tid & 3) * 32;
    const bool ok = (m0 + r) < N_EDGES;
    const float* ap = ea + (size_t)(m0 + r) * HC + cb;
    unsigned short th[32], tl[32];
#pragma unroll
    for (int q = 0; q < 8; q++) {
      float4 v = ok ? *(const float4*)(ap + q*4) : make_float4(0.f,0.f,0.f,0.f);
      float vv[4] = {v.x, v.y, v.z, v.w};
#pragma unroll
      for (int e = 0; e < 4; e++) {
        unsigned short hb = f2bf(vv[e]);
        th[q*4+e] = hb; tl[q*4+e] = f2bf(vv[e] - bf2f(hb));
      }
    }
#pragma unroll
    for (int q = 0; q < 4; q++) {
      *(bf16x8*)&ldsA[0][r][cb + q*8] = *(bf16x8*)&th[q*8];
      *(bf16x8*)&ldsA[1][r][cb + q*8] = *(bf16x8*)&tl[q*8];
    }
  }
  if (tid < 128) {
    int e  = m0 + tid;
    int ge = (e < N_EDGES) ? e : (N_EDGES - 1);
    sS[tid] = ei[ge];
    sD[tid] = ei[N_EDGES + ge];
  }

  f4v wacc[8][2];
  const f4v zf = {0.f, 0.f, 0.f, 0.f};
#pragma unroll
  for (int mt = 0; mt < 8; mt++) { wacc[mt][0] = zf; wacc[mt][1] = zf; }

  __syncthreads();

  for (int p = 0; p < 4; p++) {
    // ---- stage B1 = fw1[p*64 .. p*64+64, 0:128] hi/lo ----
    {
      const int r1 = tid >> 3, c1 = (tid & 7) * 16;
      const float* bp = fw1 + (size_t)(p*64 + r1) * HC + c1;
      unsigned short th[16], tl[16];
#pragma unroll
      for (int q = 0; q < 4; q++) {
        float4 v = *(const float4*)(bp + q*4);
        float vv[4] = {v.x, v.y, v.z, v.w};
#pragma unroll
        for (int e = 0; e < 4; e++) {
          unsigned short hb = f2bf(vv[e]);
          th[q*4+e] = hb; tl[q*4+e] = f2bf(vv[e] - bf2f(hb));
        }
      }
      *(bf16x8*)&ldsB[r1*136 + c1]        = *(bf16x8*)&th[0];
      *(bf16x8*)&ldsB[r1*136 + c1 + 8]    = *(bf16x8*)&th[8];
      *(bf16x8*)&ldsB[8704 + r1*136 + c1]     = *(bf16x8*)&tl[0];
      *(bf16x8*)&ldsB[8704 + r1*136 + c1 + 8] = *(bf16x8*)&tl[8];
    }
    __syncthreads();

    // ---- GEMM1: Tp[128,64]; wave -> rows wave*16..+16 ----
    f4v tacc[4];
#pragma unroll
    for (int nt = 0; nt < 4; nt++) tacc[nt] = zf;
    const int ar = wave*16 + l16;
#pragma unroll
    for (int kk = 0; kk < 128; kk += 32) {
      bf16x8 ah = *(const bf16x8*)&ldsA[0][ar][kk + quad*8];
      bf16x8 al = *(const bf16x8*)&ldsA[1][ar][kk + quad*8];
#pragma unroll
      for (int nt = 0; nt < 4; nt++) {
        const int br = nt*16 + l16;
        bf16x8 bh = *(const bf16x8*)&ldsB[br*136 + kk + quad*8];
        bf16x8 bl = *(const bf16x8*)&ldsB[8704 + br*136 + kk + quad*8];
        tacc[nt] = __builtin_amdgcn_mfma_f32_16x16x32_bf16(ah, bh, tacc[nt], 0, 0, 0);
        tacc[nt] = __builtin_amdgcn_mfma_f32_16x16x32_bf16(ah, bl, tacc[nt], 0, 0, 0);
        tacc[nt] = __builtin_amdgcn_mfma_f32_16x16x32_bf16(al, bh, tacc[nt], 0, 0, 0);
      }
    }
    // ssp + split -> ldsT (C layout: col = l16, row = quad*4+rr)
#pragma unroll
    for (int nt = 0; nt < 4; nt++) {
      const int col = nt*16 + l16;
      const float bz = fb1[p*64 + col];
      const int rowb = wave*16 + quad*4;
#pragma unroll
      for (int rr = 0; rr < 4; rr++) {
        float v = ssp_f(tacc[nt][rr] + bz);
        unsigned short hb = f2bf(v);
        ldsT[0][rowb+rr][col] = hb;
        ldsT[1][rowb+rr][col] = f2bf(v - bf2f(hb));
      }
    }
    __syncthreads();   // B1 reads + T writes complete

    // ---- GEMM2 partial: W += Tp @ fw2[:, p*64..p*64+64]^T ----
#pragma unroll
    for (int kc = 0; kc < 2; kc++) {
      {
        const int r2 = tid >> 1, c2 = (tid & 1) * 16;
        const float* bp = fw2 + (size_t)r2 * NFC + p*64 + kc*32 + c2;
        unsigned short th[16], tl[16];
#pragma unroll
        for (int q = 0; q < 4; q++) {
          float4 v = *(const float4*)(bp + q*4);
          float vv[4] = {v.x, v.y, v.z, v.w};
#pragma unroll
          for (int e = 0; e < 4; e++) {
            unsigned short hb = f2bf(vv[e]);
            th[q*4+e] = hb; tl[q*4+e] = f2bf(vv[e] - bf2f(hb));
          }
        }
        *(bf16x8*)&ldsB[r2*40 + c2]         = *(bf16x8*)&th[0];
        *(bf16x8*)&ldsB[r2*40 + c2 + 8]     = *(bf16x8*)&th[8];
        *(bf16x8*)&ldsB[10240 + r2*40 + c2]     = *(bf16x8*)&tl[0];
        *(bf16x8*)&ldsB[10240 + r2*40 + c2 + 8] = *(bf16x8*)&tl[8];
      }
      __syncthreads();

      bf16x8 a_h[8], a_l[8];
#pragma unroll
      for (int mt = 0; mt < 8; mt++) {
        a_h[mt] = *(const bf16x8*)&ldsT[0][mt*16 + l16][kc*32 + quad*8];
        a_l[mt] = *(const bf16x8*)&ldsT[1][mt*16 + l16][kc*32 + quad*8];
      }
#pragma unroll
      for (int nt = 0; nt < 2; nt++) {
        const int br = wave*32 + nt*16 + l16;
        bf16x8 bh = *(const bf16x8*)&ldsB[br*40 + quad*8];
        bf16x8 bl = *(const bf16x8*)&ldsB[10240 + br*40 + quad*8];
#pragma unroll
        for (int mt = 0; mt < 8; mt++) {
          wacc[mt][nt] = __builtin_amdgcn_mfma_f32_16x16x32_bf16(a_h[mt], bh, wacc[mt][nt], 0, 0, 0);
          wacc[mt][nt] = __builtin_amdgcn_mfma_f32_16x16x32_bf16(a_h[mt], bl, wacc[mt][nt], 0, 0, 0);
          wacc[mt][nt] = __builtin_amdgcn_mfma_f32_16x16x32_bf16(a_l[mt], bh, wacc[mt][nt], 0, 0, 0);
        }
      }
      __syncthreads();
    }
  }

  // ---- fused scatter epilogue ----
#pragma unroll
  for (int nt = 0; nt < 2; nt++) {
    const int col = wave*32 + nt*16 + l16;
    const float bz = fb2[col];
#pragma unroll
    for (int mt = 0; mt < 8; mt++) {
      const int rowb = mt*16 + quad*4;
#pragma unroll
      for (int rr = 0; rr < 4; rr++) {
        const int row = rowb + rr;
        const int m = m0 + row;
        if (m < N_EDGES) {
          float v = wacc[mt][nt][rr] + bz;
          float g = h1[(size_t)sS[row] * NFC + col];
          atomicAdd(&agg[(size_t)sD[row] * NFC + col], v * g);
        }
      }
    }
  }
}

// ---------------------------------------------------------------------------
__global__ void pool_kernel(const int* __restrict__ batch, const float* __restrict__ h,
                            float* __restrict__ ssum, float* __restrict__ cnt) {
  int idx = blockIdx.x * blockDim.x + threadIdx.x;
  if (idx >= N_NODES * HC) return;
  int n = idx >> 7, c = idx & 127;
  int b = batch[n];
  atomicAdd(&ssum[(size_t)b*HC + c], h[idx]);
  if (c == 0) atomicAdd(&cnt[b], 1.0f);
}

__global__ __launch_bounds__(256) void head_kernel(
    const float* __restrict__ ssum, const float* __restrict__ cnt,
    const float* __restrict__ w1, const float* __restrict__ b1,
    const float* __restrict__ w2, const float* __restrict__ b2,
    float* __restrict__ y) {
  int g = blockIdx.x;
  __shared__ float gs[HC];
  __shared__ float red[256];
  int tid = threadIdx.x;
  float inv = 1.0f / fmaxf(cnt[g], 1.0f);
  if (tid < HC) gs[tid] = ssum[(size_t)g*HC + tid] * inv;
  __syncthreads();
  float partial = 0.0f;
  for (int f = tid; f < NFFC; f += 256) {
    float acc = b1[f];
    const float* wr = w1 + (size_t)f*HC;
#pragma unroll 8
    for (int k = 0; k < HC; k++) acc = fmaf(gs[k], wr[k], acc);
    float t = 0.5f * acc * (1.0f + erff(acc * 0.70710678118654752440f));
    partial = fmaf(t, w2[f], partial);
  }
  red[tid] = partial;
  __syncthreads();
  for (int s = 128; s > 0; s >>= 1) {
    if (tid < s) red[tid] += red[tid + s];
    __syncthreads();
  }
  if (tid == 0) y[g] = red[0] + b2[0];
}

// ---------------------------------------------------------------------------
extern "C" void kernel_launch(void* const* d_in, const int* in_sizes, int n_in,
                              void* d_out, int out_size, void* d_ws, size_t ws_size,
                              hipStream_t stream) {
  const int*   x     = (const int*)  d_in[0];
  const int*   ei    = (const int*)  d_in[1];
  const float* eattr = (const float*)d_in[2];
  const int*   batch = (const int*)  d_in[3];
  const float* pos   = (const float*)d_in[4];
  const float* vert  = (const float*)d_in[5];
  const float* posw  = (const float*)d_in[6];
  const float* edgew = (const float*)d_in[7];
  const float* fw1   = (const float*)d_in[8];
  const float* fb1   = (const float*)d_in[9];
  const float* fw2   = (const float*)d_in[10];
  const float* fb2   = (const float*)d_in[11];
  const float* l1w   = (const float*)d_in[12];
  const float* l2w   = (const float*)d_in[13];
  const float* l2b   = (const float*)d_in[14];
  const float* l3w   = (const float*)d_in[15];
  const float* l3b   = (const float*)d_in[16];
  const float* emw   = (const float*)d_in[17];
  const float* emb   = (const float*)d_in[18];
  const float* hw1   = (const float*)d_in[19];
  const float* hb1   = (const float*)d_in[20];
  const float* hw2   = (const float*)d_in[21];
  const float* hb2   = (const float*)d_in[22];
  float* out = (float*)d_out;

  char* ws = (char*)d_ws;
  size_t off = 0;
  auto alloc = [&](size_t bytes) { char* p = ws + off; off += (bytes + 511) & ~(size_t)511; return p; };
  float* ea   = (float*)alloc((size_t)N_EDGES*HC*4);    // 102.4 MB
  float* h    = (float*)alloc((size_t)N_NODES*HC*4);    //  25.6 MB
  float* h1   = (float*)alloc((size_t)N_NODES*NFC*4);   //  51.2 MB (lin1 out / t2)
  float* agg  = (float*)alloc((size_t)N_NODES*NFC*4);   //  51.2 MB
  float* ssum = (float*)alloc((size_t)N_GRAPH*HC*4);
  float* cnt  = (float*)alloc((size_t)N_GRAPH*4);

  const int GN = (N_NODES + 127) / 128;   // 391
  const int GE = (N_EDGES + 127) / 128;   // 1563

  embed_kernel<<<N_NODES, 128, 0, stream>>>(x, pos, vert, posw, h);
  edgeproj_kernel<<<(N_EDGES*HC + 255)/256, 256, 0, stream>>>(eattr, edgew, ea);

  for (int i = 0; i < NLAYER; ++i) {
    // h1 = h @ l1w.T                        [N,256]
    mgemm<EPI_NONE,0><<<dim3(GN,2), 256, 0, stream>>>(
        h, l1w + (size_t)i*NFC*HC, nullptr, nullptr, h1,
        N_NODES, HC, NFC, nullptr, nullptr);
    zero_kernel<<<((N_NODES*NFC/4) + 255)/256, 256, 0, stream>>>(
        (float4*)agg, N_NODES*NFC/4);
    // fused filter MLP + scatter (no t1c round-trip)
    ffs_kernel<<<GE, 512, 0, stream>>>(
        ea, fw1 + (size_t)i*NFC*HC, fb1 + (size_t)i*NFC,
        fw2 + (size_t)i*NFC*NFC, fb2 + (size_t)i*NFC, ei, h1, agg);
    // t2(=h1) = ssp(agg @ l2w.T + l2b)      [N,128]
    mgemm<EPI_SSP,0><<<dim3(GN,1), 256, 0, stream>>>(
        agg, l2w + (size_t)i*HC*NFC, l2b + (size_t)i*HC, nullptr, h1,
        N_NODES, NFC, HC, nullptr, nullptr);
    // h = relu(t2 @ l3w.T + l3b) + h        (in place; rows disjoint per block)
    mgemm<EPI_RELU_RES,0><<<dim3(GN,1), 256, 0, stream>>>(
        h1, l3w + (size_t)i*HC*HC, l3b + (size_t)i*HC, h, h,
        N_NODES, HC, HC, nullptr, nullptr);
    // ea = tanh(cat(ea, h[src]+h[dst]) @ emw.T + emb) + ea  (gather fused)
    mgemm<EPI_TANH_RES,1><<<dim3(GE,1), 256, 0, stream>>>(
        ea, emw + (size_t)i*HC*2*HC, emb + (size_t)i*HC, ea, ea,
        N_EDGES, 2*HC, HC, ei, h);
  }

  zero_kernel<<<((N_GRAPH*HC/4) + 255)/256, 256, 0, stream>>>((float4*)ssum, N_GRAPH*HC/4);
  zero_kernel<<<((N_GRAPH/4) + 255)/256, 256, 0, stream>>>((float4*)cnt, N_GRAPH/4);
  pool_kernel<<<(N_NODES*HC + 255)/256, 256, 0, stream>>>(batch, h, ssum, cnt);
  head_kernel<<<N_GRAPH, 256, 0, stream>>>(ssum, cnt, hw1, hb1, hw2, hb2, out);
}